// Round 15
// baseline (288.030 us; speedup 1.0000x reference)
//
#include <hip/hip_runtime.h>

#define NN 400000
#define NE 400000

typedef __attribute__((ext_vector_type(4))) float f32x4;
typedef __attribute__((ext_vector_type(8))) short s16x8;
typedef unsigned short ushort_t;

__device__ __forceinline__ ushort_t f2bf(float f) {
    union { float f; unsigned int u; } c;
    c.f = f;
    unsigned int u = c.u;
    u = u + 0x7fffu + ((u >> 16) & 1u);
    return (ushort_t)(u >> 16);
}
__device__ __forceinline__ float bf2f(ushort_t v) {
    union { unsigned int u; float f; } c;
    c.u = ((unsigned int)v) << 16;
    return c.f;
}

// --- detect int64 edge_index: 64 parallel lane loads + ballot ---
__global__ void k_detect(const int* __restrict__ ei_raw, int* __restrict__ flag) {
    const int l = threadIdx.x;              // 64 threads
    const int v = ei_raw[2 * l + 1];
    const unsigned long long b = __ballot(v != 0);
    if (l == 0) flag[0] = (b == 0ULL) ? 1 : 0;
}

__global__ void k_cvt_idx(const int* __restrict__ ei_raw, const int* __restrict__ flag,
                          int* __restrict__ ei32) {
    const int i = blockIdx.x * 256 + threadIdx.x;
    const int f = flag[0];
    ei32[i] = f ? ei_raw[2 * i] : ei_raw[i];
}

// --- W [128,512] f32 -> bf16, plain row-major ---
__global__ void k_wcvt(const float* __restrict__ W, ushort_t* __restrict__ wbf) {
    const int i = blockIdx.x * 256 + threadIdx.x;
    wbf[i] = f2bf(W[i]);
}

// --- att -> MFMA B-fragment table (4KB): attB[ks][lane] = bf16x8 of
//     B[col = lane&15][k = ks*32 + (lane>>4)*8 + m]; col 0..3 = u_h (front att),
//     col 4..7 = v_h (back att), col 8..15 = 0. Same B mapping as k_gemm's wbf. ---
__global__ void k_attprep(const float* __restrict__ att, ushort_t* __restrict__ attB) {
    const int t = threadIdx.x;          // 256
    const int ks = t >> 6, lane = t & 63;
    const int col = lane & 15, kg = lane >> 4;
    const int jb = ks * 32 + kg * 8;
    s16x8 pk;
#pragma unroll
    for (int m = 0; m < 8; m++) {
        float v = 0.f;
        if (col < 4)      v = att[col * 256 + jb + m];
        else if (col < 8) v = att[(col - 4) * 256 + 128 + jb + m];
        pk[m] = (short)f2bf(v);
    }
    *(s16x8*)(attB + (size_t)(ks * 64 + lane) * 8) = pk;
}

// --- fused u,v + x->bf16, MFMA version (replaces the shuffle-butterfly kernel:
//     ~30 DS-pipe ops per 512B loaded -> 4 MFMAs per 16 nodes, zero cross-lane).
//     A/B/C fragment mappings identical to the numerically-verified k_gemm ones.
//     Wave handles 16 nodes: lane&15 = node, (lane>>4)*8 = k-subgroup. ---
__global__ __launch_bounds__(256) void k_uv_mfma(
    const float* __restrict__ x, const ushort_t* __restrict__ attB,
    ushort_t* __restrict__ xbf, float* __restrict__ uv) {
    const int lane = threadIdx.x & 63;
    const int wv = threadIdx.x >> 6;     // 4 waves/block
    const int kg = lane >> 4;

    // B fragments (tiny, L1-resident; remat harmless)
    s16x8 bfr[4];
#pragma unroll
    for (int ks = 0; ks < 4; ks++)
        bfr[ks] = *(const s16x8*)(attB + (size_t)(ks * 64 + lane) * 8);

    const f32x4 zero = {0.f, 0.f, 0.f, 0.f};
    const int ntiles = NN / 64;

#pragma unroll 1
    for (int tile = blockIdx.x; tile < ntiles; tile += gridDim.x) {
        const int n = tile * 64 + wv * 16 + (lane & 15);
        const float* xr = x + (size_t)n * 128 + kg * 8;
        ushort_t* xw = xbf + (size_t)n * 128 + kg * 8;

        s16x8 afr[4];
#pragma unroll
        for (int ks = 0; ks < 4; ks++) {
            const f32x4 a0 = *(const f32x4*)(xr + ks * 32);
            const f32x4 a1 = *(const f32x4*)(xr + ks * 32 + 4);
            s16x8 pk;
#pragma unroll
            for (int m = 0; m < 4; m++) { pk[m] = (short)f2bf(a0[m]); pk[4 + m] = (short)f2bf(a1[m]); }
            afr[ks] = pk;
            *(s16x8*)(xw + ks * 32) = pk;    // xbf output (same bytes as A-frag)
        }
        f32x4 c = zero;
#pragma unroll
        for (int ks = 0; ks < 4; ks++)
            c = __builtin_amdgcn_mfma_f32_16x16x32_bf16(afr[ks], bfr[ks], c, 0, 0, 0);

        // C: col = lane&15 (0..7 used), node-row = (lane>>4)*4 + r
        const int colc = lane & 15;
        if (colc < 8) {
#pragma unroll
            for (int r = 0; r < 4; r++) {
                const int nn = tile * 64 + wv * 16 + kg * 4 + r;
                uv[(size_t)nn * 8 + colc] = c[r];
            }
        }
    }
}

// --- per-edge: leaky_relu -> head softmax -> p=exp(score), atomic denom ---
__global__ void k_edge(const int* __restrict__ ei, const float* __restrict__ uv,
                       float* __restrict__ p, float* __restrict__ denom) {
    const int e = blockIdx.x * 256 + threadIdx.x;
    if (e >= NE) return;
    const int row = ei[e];
    const int col = ei[NE + e];
    const f32x4 u = *(const f32x4*)(uv + (size_t)row * 8);
    const f32x4 v = *(const f32x4*)(uv + (size_t)col * 8 + 4);
    float s[4];
    float mx = -1e30f;
#pragma unroll
    for (int h = 0; h < 4; h++) {
        float t = u[h] + v[h];
        t = t > 0.f ? t : 0.01f * t;
        s[h] = t;
        mx = fmaxf(mx, t);
    }
    float ex[4], sum = 0.f;
#pragma unroll
    for (int h = 0; h < 4; h++) { ex[h] = __expf(s[h] - mx); sum += ex[h]; }
    const float inv = 1.f / sum;
    f32x4 pv;
#pragma unroll
    for (int h = 0; h < 4; h++) pv[h] = __expf(ex[h] * inv);
    *(f32x4*)(p + (size_t)e * 4) = pv;
#pragma unroll
    for (int h = 0; h < 4; h++) atomicAdd(denom + (size_t)row * 4 + h, pv[h]);
}

// --- alpha4[e] = p[e,:] / denom[row[e],:] ---
__global__ void k_alpha(const int* __restrict__ ei, const float* __restrict__ p,
                        const float* __restrict__ denom, float* __restrict__ alpha4) {
    const int e = blockIdx.x * 256 + threadIdx.x;
    if (e >= NE) return;
    const int row = ei[e];
    const f32x4 pv = *(const f32x4*)(p + (size_t)e * 4);
    const f32x4 dv = *(const f32x4*)(denom + (size_t)row * 4);
    *(f32x4*)(alpha4 + (size_t)e * 4) = pv / dv;
}

// --- persistent head-split GEMM, v8 (best measured: 120.6 µs — unchanged) ---
__global__ __launch_bounds__(1024, 4) void k_gemm(
    const ushort_t* __restrict__ xbf, const int* __restrict__ ei,
    const float* __restrict__ alpha4, const ushort_t* __restrict__ wbf,
    const float* __restrict__ bias, float* __restrict__ out)
{
    __shared__ __align__(16) ushort_t Bsm[128 * 512];   // 128KB [icol][k], swz ((icol&15)<<4)
    __shared__ __align__(16) ushort_t Asm[2][64 * 128]; // 2x16KB [e][k],  swz ((e&15)<<4)

    const int tid = threadIdx.x;
    const int lane = tid & 63;
    const int w = tid >> 6;       // 0..15
    const int eg = w & 1;         // edge group: rows eg*32..+32
    const int cg = w >> 1;        // col group:  cols cg*16..+16

    // stage W once (r10-proven conflict-free map)
    {
        const int icol = tid & 127, seg = tid >> 7;
        const ushort_t* src = wbf + icol * 512 + seg * 64;
#pragma unroll
        for (int m = 0; m < 8; m++) {
            const s16x8 v = *(const s16x8*)(src + m * 8);
            const int byte = icol * 1024 + ((seg * 128 + m * 16) ^ ((icol & 15) << 4));
            *(s16x8*)((char*)Bsm + byte) = v;
        }
    }
    const int icol = cg * 16 + (lane & 15);
    const float bias_r = bias[icol];

    const f32x4 zero = {0.f, 0.f, 0.f, 0.f};
    const int ntiles = NE / 64;
    const int stride = gridDim.x;

    auto STAGE = [&](int tt, int b) {
        const int rr = w * 4 + (lane >> 4);
        const int col = ei[NE + tt * 64 + rr];
        const int c = (lane & 15) ^ (rr & 15);
        const ushort_t* src = xbf + (size_t)col * 128 + c * 8;
        __builtin_amdgcn_global_load_lds(
            (const __attribute__((address_space(1))) unsigned int*)src,
            (__attribute__((address_space(3))) unsigned int*)((char*)Asm[b] + w * 1024),
            16, 0, 0);
    };

    int t = blockIdx.x;
    int cur = 0;
    if (t < ntiles) STAGE(t, 0);

#pragma unroll 1
    for (; t < ntiles; t += stride) {
        __syncthreads();
        const int tn = t + stride;
        if (tn < ntiles) STAGE(tn, cur ^ 1);

        const f32x4 alp = *(const f32x4*)(alpha4 + (size_t)(t * 64 + eg * 32 + (lane & 31)) * 4);

        s16x8 af[2][4];
#pragma unroll
        for (int eb = 0; eb < 2; eb++) {
            const int rr = eg * 32 + eb * 16 + (lane & 15);
#pragma unroll
            for (int ks = 0; ks < 4; ks++) {
                const int byte = rr * 256 + ((ks * 64 + (lane >> 4) * 16) ^ ((rr & 15) << 4));
                af[eb][ks] = *(const s16x8*)((const char*)Asm[cur] + byte);
            }
        }

        f32x4 fin[2];
        fin[0] = zero; fin[1] = zero;

#pragma unroll
        for (int h = 0; h < 4; h++) {
            s16x8 bfr[4];
#pragma unroll
            for (int ks = 0; ks < 4; ks++) {
                const int byte = icol * 1024 +
                    ((h * 256 + ks * 64 + (lane >> 4) * 16) ^ ((icol & 15) << 4));
                bfr[ks] = *(const s16x8*)((const char*)Bsm + byte);
            }
#pragma unroll
            for (int eb = 0; eb < 2; eb++) {
                f32x4 a = __builtin_amdgcn_mfma_f32_16x16x32_bf16(af[eb][0], bfr[0], zero, 0, 0, 0);
#pragma unroll
                for (int ks = 1; ks < 4; ks++)
                    a = __builtin_amdgcn_mfma_f32_16x16x32_bf16(af[eb][ks], bfr[ks], a, 0, 0, 0);
                f32x4 av;
#pragma unroll
                for (int r = 0; r < 4; r++)
                    av[r] = __shfl(alp[h], eb * 16 + (lane >> 4) * 4 + r, 64);
                fin[eb] += av * a;
            }
        }
#pragma unroll
        for (int eb = 0; eb < 2; eb++) {
#pragma unroll
            for (int r = 0; r < 4; r++) {
                const int e = t * 64 + eg * 32 + eb * 16 + (lane >> 4) * 4 + r;
                const size_t off = (size_t)e * 128 + icol;
                out[off] = fin[eb][r] + bias_r + bf2f(xbf[off]);
            }
        }
        cur ^= 1;
    }
}

extern "C" void kernel_launch(void* const* d_in, const int* in_sizes, int n_in,
                              void* d_out, int out_size, void* d_ws, size_t ws_size,
                              hipStream_t stream) {
    const float* x      = (const float*)d_in[0];
    const int*   ei_raw = (const int*)d_in[1];
    const float* att    = (const float*)d_in[2];
    const float* W      = (const float*)d_in[3];
    const float* b      = (const float*)d_in[4];
    float* out = (float*)d_out;

    char* ws = (char*)d_ws;
    float*    uv      = (float*)(ws);                     // N*8 f32   = 12.8 MB
    float*    p       = (float*)(ws + 12800000);          // E*4 f32   =  6.4 MB
    float*    denom   = (float*)(ws + 19200000);          // N*4 f32   =  6.4 MB
    float*    alpha4  = (float*)(ws + 25600000);          // E*4 f32   =  6.4 MB
    ushort_t* wbf     = (ushort_t*)(ws + 32000000);       // 128 KB
    int*      flag    = (int*)(ws + 32200000);            // 4 B
    ushort_t* attB    = (ushort_t*)(ws + 32200064);       // 4 KB
    int*      ei32    = (int*)(ws + 32210048);            // 3.2 MB
    ushort_t* xbf     = (ushort_t*)(ws + 35420224);       // N*128 bf16 = 102.4 MB

    hipMemsetAsync(denom, 0, (size_t)NN * 4 * sizeof(float), stream);
    k_detect<<<1, 64, 0, stream>>>(ei_raw, flag);
    k_cvt_idx<<<2 * NE / 256, 256, 0, stream>>>(ei_raw, flag, ei32);
    k_wcvt<<<256, 256, 0, stream>>>(W, wbf);
    k_attprep<<<1, 256, 0, stream>>>(att, attB);
    k_uv_mfma<<<2048, 256, 0, stream>>>(x, attB, xbf, uv);
    k_edge<<<(NE + 255) / 256, 256, 0, stream>>>(ei32, uv, p, denom);
    k_alpha<<<(NE + 255) / 256, 256, 0, stream>>>(ei32, p, denom, alpha4);
    k_gemm<<<256, 1024, 0, stream>>>(xbf, ei32, alpha4, wbf, b, out);
}

// Round 16
// 264.039 us; speedup vs baseline: 1.0909x; 1.0909x over previous
//
#include <hip/hip_runtime.h>

#define NN 400000
#define NE 400000

typedef __attribute__((ext_vector_type(4))) float f32x4;
typedef __attribute__((ext_vector_type(8))) short s16x8;
typedef unsigned short ushort_t;

__device__ __forceinline__ ushort_t f2bf(float f) {
    union { float f; unsigned int u; } c;
    c.f = f;
    unsigned int u = c.u;
    u = u + 0x7fffu + ((u >> 16) & 1u);
    return (ushort_t)(u >> 16);
}
__device__ __forceinline__ float bf2f(ushort_t v) {
    union { unsigned int u; float f; } c;
    c.u = ((unsigned int)v) << 16;
    return c.f;
}

// --- detect int64 edge_index: 64 parallel lane loads + ballot ---
__global__ void k_detect(const int* __restrict__ ei_raw, int* __restrict__ flag) {
    const int l = threadIdx.x;              // 64 threads
    const int v = ei_raw[2 * l + 1];
    const unsigned long long b = __ballot(v != 0);
    if (l == 0) flag[0] = (b == 0ULL) ? 1 : 0;
}

// --- merged prep: blocks 0..255 convert W -> bf16; block 256 builds attB table ---
__global__ void k_prep(const float* __restrict__ W, ushort_t* __restrict__ wbf,
                       const float* __restrict__ att, ushort_t* __restrict__ attB) {
    if (blockIdx.x < 256) {
        const int i = blockIdx.x * 256 + threadIdx.x;
        wbf[i] = f2bf(W[i]);
    } else {
        const int t = threadIdx.x;          // 256
        const int ks = t >> 6, lane = t & 63;
        const int col = lane & 15, kg = lane >> 4;
        const int jb = ks * 32 + kg * 8;
        s16x8 pk;
#pragma unroll
        for (int m = 0; m < 8; m++) {
            float v = 0.f;
            if (col < 4)      v = att[col * 256 + jb + m];
            else if (col < 8) v = att[(col - 4) * 256 + 128 + jb + m];
            pk[m] = (short)f2bf(v);
        }
        *(s16x8*)(attB + (size_t)(ks * 64 + lane) * 8) = pk;
    }
}

// --- fused u,v + x->bf16, MFMA version (r15, unchanged) ---
__global__ __launch_bounds__(256) void k_uv_mfma(
    const float* __restrict__ x, const ushort_t* __restrict__ attB,
    ushort_t* __restrict__ xbf, float* __restrict__ uv) {
    const int lane = threadIdx.x & 63;
    const int wv = threadIdx.x >> 6;     // 4 waves/block
    const int kg = lane >> 4;

    s16x8 bfr[4];
#pragma unroll
    for (int ks = 0; ks < 4; ks++)
        bfr[ks] = *(const s16x8*)(attB + (size_t)(ks * 64 + lane) * 8);

    const f32x4 zero = {0.f, 0.f, 0.f, 0.f};
    const int ntiles = NN / 64;

#pragma unroll 1
    for (int tile = blockIdx.x; tile < ntiles; tile += gridDim.x) {
        const int n = tile * 64 + wv * 16 + (lane & 15);
        const float* xr = x + (size_t)n * 128 + kg * 8;
        ushort_t* xw = xbf + (size_t)n * 128 + kg * 8;

        s16x8 afr[4];
#pragma unroll
        for (int ks = 0; ks < 4; ks++) {
            const f32x4 a0 = *(const f32x4*)(xr + ks * 32);
            const f32x4 a1 = *(const f32x4*)(xr + ks * 32 + 4);
            s16x8 pk;
#pragma unroll
            for (int m = 0; m < 4; m++) { pk[m] = (short)f2bf(a0[m]); pk[4 + m] = (short)f2bf(a1[m]); }
            afr[ks] = pk;
            *(s16x8*)(xw + ks * 32) = pk;    // xbf output (same bytes as A-frag)
        }
        f32x4 c = zero;
#pragma unroll
        for (int ks = 0; ks < 4; ks++)
            c = __builtin_amdgcn_mfma_f32_16x16x32_bf16(afr[ks], bfr[ks], c, 0, 0, 0);

        const int colc = lane & 15;
        if (colc < 8) {
#pragma unroll
            for (int r = 0; r < 4; r++) {
                const int nn = tile * 64 + wv * 16 + kg * 4 + r;
                uv[(size_t)nn * 8 + colc] = c[r];
            }
        }
    }
}

// --- per-edge (fused idx-convert): leaky_relu -> head softmax -> p=exp, atomic
//     denom; also emits ei32 (row,col) for k_alpha / k_gemm ---
__global__ void k_edge(const int* __restrict__ ei_raw, const int* __restrict__ flag,
                       const float* __restrict__ uv, float* __restrict__ p,
                       float* __restrict__ denom, int* __restrict__ ei32) {
    const int e = blockIdx.x * 256 + threadIdx.x;
    if (e >= NE) return;
    const int f = flag[0];
    const int row = f ? ei_raw[2 * e] : ei_raw[e];
    const int col = f ? ei_raw[2 * (NE + e)] : ei_raw[NE + e];
    ei32[e] = row;
    ei32[NE + e] = col;
    const f32x4 u = *(const f32x4*)(uv + (size_t)row * 8);
    const f32x4 v = *(const f32x4*)(uv + (size_t)col * 8 + 4);
    float s[4];
    float mx = -1e30f;
#pragma unroll
    for (int h = 0; h < 4; h++) {
        float t = u[h] + v[h];
        t = t > 0.f ? t : 0.01f * t;
        s[h] = t;
        mx = fmaxf(mx, t);
    }
    float ex[4], sum = 0.f;
#pragma unroll
    for (int h = 0; h < 4; h++) { ex[h] = __expf(s[h] - mx); sum += ex[h]; }
    const float inv = 1.f / sum;
    f32x4 pv;
#pragma unroll
    for (int h = 0; h < 4; h++) pv[h] = __expf(ex[h] * inv);
    *(f32x4*)(p + (size_t)e * 4) = pv;
#pragma unroll
    for (int h = 0; h < 4; h++) atomicAdd(denom + (size_t)row * 4 + h, pv[h]);
}

// --- alpha4[e] = p[e,:] / denom[row[e],:] ---
__global__ void k_alpha(const int* __restrict__ ei, const float* __restrict__ p,
                        const float* __restrict__ denom, float* __restrict__ alpha4) {
    const int e = blockIdx.x * 256 + threadIdx.x;
    if (e >= NE) return;
    const int row = ei[e];
    const f32x4 pv = *(const f32x4*)(p + (size_t)e * 4);
    const f32x4 dv = *(const f32x4*)(denom + (size_t)row * 4);
    *(f32x4*)(alpha4 + (size_t)e * 4) = pv / dv;
}

// --- persistent head-split GEMM, v11 = v8 + NONTEMPORAL out stores.
//     out (203MB) is never re-read; regular stores evict the L3-resident xbf
//     (102MB, read 2x by this kernel) -> FETCH was 130MB. nt stores bypass L3
//     retention so the xbf gather + residual re-read stay L3-hits. ---
__global__ __launch_bounds__(1024, 4) void k_gemm(
    const ushort_t* __restrict__ xbf, const int* __restrict__ ei,
    const float* __restrict__ alpha4, const ushort_t* __restrict__ wbf,
    const float* __restrict__ bias, float* __restrict__ out)
{
    __shared__ __align__(16) ushort_t Bsm[128 * 512];   // 128KB [icol][k], swz ((icol&15)<<4)
    __shared__ __align__(16) ushort_t Asm[2][64 * 128]; // 2x16KB [e][k],  swz ((e&15)<<4)

    const int tid = threadIdx.x;
    const int lane = tid & 63;
    const int w = tid >> 6;       // 0..15
    const int eg = w & 1;         // edge group: rows eg*32..+32
    const int cg = w >> 1;        // col group:  cols cg*16..+16

    // stage W once (r10-proven conflict-free map)
    {
        const int icol = tid & 127, seg = tid >> 7;
        const ushort_t* src = wbf + icol * 512 + seg * 64;
#pragma unroll
        for (int m = 0; m < 8; m++) {
            const s16x8 v = *(const s16x8*)(src + m * 8);
            const int byte = icol * 1024 + ((seg * 128 + m * 16) ^ ((icol & 15) << 4));
            *(s16x8*)((char*)Bsm + byte) = v;
        }
    }
    const int icol = cg * 16 + (lane & 15);
    const float bias_r = bias[icol];

    const f32x4 zero = {0.f, 0.f, 0.f, 0.f};
    const int ntiles = NE / 64;
    const int stride = gridDim.x;

    auto STAGE = [&](int tt, int b) {
        const int rr = w * 4 + (lane >> 4);
        const int col = ei[NE + tt * 64 + rr];
        const int c = (lane & 15) ^ (rr & 15);
        const ushort_t* src = xbf + (size_t)col * 128 + c * 8;
        __builtin_amdgcn_global_load_lds(
            (const __attribute__((address_space(1))) unsigned int*)src,
            (__attribute__((address_space(3))) unsigned int*)((char*)Asm[b] + w * 1024),
            16, 0, 0);
    };

    int t = blockIdx.x;
    int cur = 0;
    if (t < ntiles) STAGE(t, 0);

#pragma unroll 1
    for (; t < ntiles; t += stride) {
        __syncthreads();
        const int tn = t + stride;
        if (tn < ntiles) STAGE(tn, cur ^ 1);

        const f32x4 alp = *(const f32x4*)(alpha4 + (size_t)(t * 64 + eg * 32 + (lane & 31)) * 4);

        s16x8 af[2][4];
#pragma unroll
        for (int eb = 0; eb < 2; eb++) {
            const int rr = eg * 32 + eb * 16 + (lane & 15);
#pragma unroll
            for (int ks = 0; ks < 4; ks++) {
                const int byte = rr * 256 + ((ks * 64 + (lane >> 4) * 16) ^ ((rr & 15) << 4));
                af[eb][ks] = *(const s16x8*)((const char*)Asm[cur] + byte);
            }
        }

        f32x4 fin[2];
        fin[0] = zero; fin[1] = zero;

#pragma unroll
        for (int h = 0; h < 4; h++) {
            s16x8 bfr[4];
#pragma unroll
            for (int ks = 0; ks < 4; ks++) {
                const int byte = icol * 1024 +
                    ((h * 256 + ks * 64 + (lane >> 4) * 16) ^ ((icol & 15) << 4));
                bfr[ks] = *(const s16x8*)((const char*)Bsm + byte);
            }
#pragma unroll
            for (int eb = 0; eb < 2; eb++) {
                f32x4 a = __builtin_amdgcn_mfma_f32_16x16x32_bf16(af[eb][0], bfr[0], zero, 0, 0, 0);
#pragma unroll
                for (int ks = 1; ks < 4; ks++)
                    a = __builtin_amdgcn_mfma_f32_16x16x32_bf16(af[eb][ks], bfr[ks], a, 0, 0, 0);
                f32x4 av;
#pragma unroll
                for (int r = 0; r < 4; r++)
                    av[r] = __shfl(alp[h], eb * 16 + (lane >> 4) * 4 + r, 64);
                fin[eb] += av * a;
            }
        }
        // epilogue: + bias + residual; NONTEMPORAL out stores (no L3 pollution)
#pragma unroll
        for (int eb = 0; eb < 2; eb++) {
#pragma unroll
            for (int r = 0; r < 4; r++) {
                const int e = t * 64 + eg * 32 + eb * 16 + (lane >> 4) * 4 + r;
                const size_t off = (size_t)e * 128 + icol;
                __builtin_nontemporal_store(fin[eb][r] + bias_r + bf2f(xbf[off]), &out[off]);
            }
        }
        cur ^= 1;
    }
}

extern "C" void kernel_launch(void* const* d_in, const int* in_sizes, int n_in,
                              void* d_out, int out_size, void* d_ws, size_t ws_size,
                              hipStream_t stream) {
    const float* x      = (const float*)d_in[0];
    const int*   ei_raw = (const int*)d_in[1];
    const float* att    = (const float*)d_in[2];
    const float* W      = (const float*)d_in[3];
    const float* b      = (const float*)d_in[4];
    float* out = (float*)d_out;

    char* ws = (char*)d_ws;
    float*    uv      = (float*)(ws);                     // N*8 f32   = 12.8 MB
    float*    p       = (float*)(ws + 12800000);          // E*4 f32   =  6.4 MB
    float*    denom   = (float*)(ws + 19200000);          // N*4 f32   =  6.4 MB
    float*    alpha4  = (float*)(ws + 25600000);          // E*4 f32   =  6.4 MB
    ushort_t* wbf     = (ushort_t*)(ws + 32000000);       // 128 KB
    int*      flag    = (int*)(ws + 32200000);            // 4 B
    ushort_t* attB    = (ushort_t*)(ws + 32200064);       // 4 KB
    int*      ei32    = (int*)(ws + 32210048);            // 3.2 MB
    ushort_t* xbf     = (ushort_t*)(ws + 35420224);       // N*128 bf16 = 102.4 MB

    hipMemsetAsync(denom, 0, (size_t)NN * 4 * sizeof(float), stream);
    k_detect<<<1, 64, 0, stream>>>(ei_raw, flag);
    k_prep<<<257, 256, 0, stream>>>(W, wbf, att, attB);
    k_uv_mfma<<<2048, 256, 0, stream>>>(x, attB, xbf, uv);
    k_edge<<<(NE + 255) / 256, 256, 0, stream>>>(ei_raw, flag, uv, p, denom, ei32);
    k_alpha<<<(NE + 255) / 256, 256, 0, stream>>>(ei32, p, denom, alpha4);
    k_gemm<<<256, 1024, 0, stream>>>(xbf, ei32, alpha4, wbf, b, out);
}